// Round 3
// baseline (663.918 us; speedup 1.0000x reference)
//
#include <hip/hip_runtime.h>
#include <stdint.h>

// SubdivideMeshes: verts (N,V,3) f32, faces (F,3) i32, edges (E,2) i32,
// face_to_edge (F,3) i32.
// Out (flat f32): new_verts (N, V+E, 3) then new_faces (4F, 3) as floats.
//
// Single fused dispatch, blockIdx.x-partitioned: copy | midpoints | faces.
// NOTE (measured r2): timed region includes the harness's 2.011GB poison fill
// (~320us) -> hard floor. Our kernel is <318us; this round targets store/load
// request efficiency (coalesced float4 via LDS staging in phases A and B).

#define GRID_S 1024
#define V_CONST (GRID_S * GRID_S)        // 1,048,576
#define PER_BATCH (V_CONST * 3)          // 3,145,728 floats per batch
#define CPB 768                          // copy blocks/batch (4096 floats each)

typedef float f4v __attribute__((ext_vector_type(4)));
typedef float f2v __attribute__((ext_vector_type(2)));

__device__ __forceinline__ void store12(float* p, f4v w0, f4v w1, f4v w2) {
    const uintptr_t a = (uintptr_t)p;
    if ((a & 15) == 0) {
        f4v* q = reinterpret_cast<f4v*>(p);
        q[0] = w0; q[1] = w1; q[2] = w2;
    } else if ((a & 7) == 0) {
        f2v* q = reinterpret_cast<f2v*>(p);
        q[0] = (f2v){w0[0], w0[1]};
        q[1] = (f2v){w0[2], w0[3]};
        q[2] = (f2v){w1[0], w1[1]};
        q[3] = (f2v){w1[2], w1[3]};
        q[4] = (f2v){w2[0], w2[1]};
        q[5] = (f2v){w2[2], w2[3]};
    } else {
#pragma unroll
        for (int i = 0; i < 4; ++i) p[i] = w0[i];
#pragma unroll
        for (int i = 0; i < 4; ++i) p[4 + i] = w1[i];
#pragma unroll
        for (int i = 0; i < 4; ++i) p[8 + i] = w2[i];
    }
}

__global__ __launch_bounds__(256) void fused_k(
    const float* __restrict__ verts,
    const int2*  __restrict__ edges,
    const int*   __restrict__ faces,
    const int*   __restrict__ fte,
    float* __restrict__ out,
    int E, int F, int N, int rowStride3, int baseOut,
    int Bcopy, int Bmid) {

    __shared__ float lds[4100];
    const int b = blockIdx.x;
    const int tid = threadIdx.x;

    if (b < Bcopy) {
        // ---------------- phase A: verts copy, LDS-shifted aligned float4 --
        const int n  = b / CPB;                  // constexpr divisor
        const int cb = b - n * CPB;
        const int d0 = n * rowStride3;           // odd stride: per-batch shift
        const float* __restrict__ src = verts + n * PER_BATCH;
        float* __restrict__ dst = out + d0;
        const int pad = (4 - (d0 & 3)) & 3;      // floats until dst 16B-aligned
        const int main4 = (PER_BATCH - pad) >> 2;
        const int sBase = cb * 4096;             // block's src window (floats)

        // aligned vector loads into LDS (src window always within batch)
#pragma unroll
        for (int j = 0; j < 4; ++j) {
            const int o = 1024 * j + 4 * tid;
            *reinterpret_cast<f4v*>(&lds[o]) =
                *reinterpret_cast<const f4v*>(src + sBase + o);
        }
        if (pad && tid < 3) {
            const int si = sBase + 4096 + tid;   // shift spill-over (3 floats)
            lds[4096 + tid] = (si < PER_BATCH) ? src[si] : 0.0f;
        }
        __syncthreads();

        // dst-aligned vector stores (shifted read from LDS)
#pragma unroll
        for (int j = 0; j < 4; ++j) {
            const int loc = 1024 * j + 4 * tid;
            const int k4 = cb * 1024 + (loc >> 2);
            if (k4 < main4) {
                f4v v;
                if (pad == 0) {
                    v = *reinterpret_cast<const f4v*>(&lds[loc]);
                } else {
                    v[0] = lds[loc + pad + 0];
                    v[1] = lds[loc + pad + 1];
                    v[2] = lds[loc + pad + 2];
                    v[3] = lds[loc + pad + 3];
                }
                *reinterpret_cast<f4v*>(dst + pad + 4 * k4) = v;
            }
        }
        if (cb == 0 && tid == 0) {
            for (int i = 0; i < pad; ++i) dst[i] = src[i];
            const int rem = (PER_BATCH - pad) & 3;
            for (int i = PER_BATCH - rem; i < PER_BATCH; ++i) dst[i] = src[i];
        }
        return;
    }

    if (b < Bcopy + Bmid) {
        // ---------------- phase B: edge midpoints --------------------------
        const int blk = b - Bcopy;
        const int e0 = blk << 8;
        const int e  = e0 + tid;

        if ((e0 + 256 <= E) && (N == 8)) {
            // full block fast path: all 48 gathers up-front (max MLP),
            // then LDS-staged coalesced float4 stores per batch.
            const int2 ed = edges[e];
            const int i0 = 3 * ed.x;
            const int i1 = 3 * ed.y;
            float mx[8], my[8], mz[8];
            const float* __restrict__ vb = verts;
#pragma unroll
            for (int n = 0; n < 8; ++n) {
                mx[n] = 0.5f * (vb[i0 + 0] + vb[i1 + 0]);
                my[n] = 0.5f * (vb[i0 + 1] + vb[i1 + 1]);
                mz[n] = 0.5f * (vb[i0 + 2] + vb[i1 + 2]);
                vb += PER_BATCH;
            }
            const int gb = (V_CONST + e0) * 3;
#pragma unroll
            for (int n = 0; n < 8; ++n) {
                if (n) __syncthreads();          // protect LDS reuse
                lds[3 * tid + 0] = mx[n];        // stride-3: conflict-free
                lds[3 * tid + 1] = my[n];
                lds[3 * tid + 2] = mz[n];
                __syncthreads();
                const int g0 = gb + n * rowStride3;
                const int head = (4 - (g0 & 3)) & 3;
                const int m4 = (768 - head) >> 2;
                if (tid < m4) {
                    const int l = head + (tid << 2);
                    f4v v;
                    v[0] = lds[l + 0]; v[1] = lds[l + 1];
                    v[2] = lds[l + 2]; v[3] = lds[l + 3];
                    *reinterpret_cast<f4v*>(out + g0 + l) = v;
                } else if (tid == m4) {
                    for (int j = 0; j < head; ++j) out[g0 + j] = lds[j];
                    const int tail = (768 - head) & 3;
                    for (int j = 0; j < tail; ++j)
                        out[g0 + 768 - tail + j] = lds[768 - tail + j];
                }
            }
        } else if (e < E) {
            // tail block / generic-N fallback: scalar path
            const int2 ed = edges[e];
            const int i0 = 3 * ed.x;
            const int i1 = 3 * ed.y;
            const float* __restrict__ vb = verts;
            float* __restrict__ o = out + (V_CONST + e) * 3;
            for (int n = 0; n < N; ++n) {
                o[0] = 0.5f * (vb[i0 + 0] + vb[i1 + 0]);
                o[1] = 0.5f * (vb[i0 + 1] + vb[i1 + 1]);
                o[2] = 0.5f * (vb[i0 + 2] + vb[i1 + 2]);
                vb += PER_BATCH;
                o  += rowStride3;
            }
        }
        return;
    }

    // -------------------- phase C: new faces -------------------------------
    const int t = (b - Bcopy - Bmid) * 256 + tid;
    const int mainT = F >> 2;
    float* __restrict__ base = out + baseOut;

    if (t < mainT) {
        const int4* f4 = reinterpret_cast<const int4*>(faces) + 3 * t;
        const int4* q4 = reinterpret_cast<const int4*>(fte) + 3 * t;
        const int4 p0 = f4[0], p1 = f4[1], p2 = f4[2];
        const int4 q0 = q4[0], q1 = q4[1], q2 = q4[2];

        const float a0 = (float)p0.x, a1 = (float)p0.w, a2 = (float)p1.z, a3 = (float)p2.y;
        const float b0 = (float)p0.y, b1 = (float)p1.x, b2 = (float)p1.w, b3 = (float)p2.z;
        const float c0 = (float)p0.z, c1 = (float)p1.y, c2 = (float)p2.x, c3 = (float)p2.w;

        const float e00 = (float)(q0.x + V_CONST), e01 = (float)(q0.w + V_CONST),
                    e02 = (float)(q1.z + V_CONST), e03 = (float)(q2.y + V_CONST);
        const float e10 = (float)(q0.y + V_CONST), e11 = (float)(q1.x + V_CONST),
                    e12 = (float)(q1.w + V_CONST), e13 = (float)(q2.z + V_CONST);
        const float e20 = (float)(q0.z + V_CONST), e21 = (float)(q1.y + V_CONST),
                    e22 = (float)(q2.x + V_CONST), e23 = (float)(q2.w + V_CONST);

        const int off = 12 * t;
        const int segF = 3 * F;

        store12(base + off,
                (f4v){a0, e20, e10, a1}, (f4v){e21, e11, a2, e22}, (f4v){e12, a3, e23, e13});
        store12(base + segF + off,
                (f4v){b0, e00, e20, b1}, (f4v){e01, e21, b2, e02}, (f4v){e22, b3, e03, e23});
        store12(base + 2 * segF + off,
                (f4v){c0, e10, e00, c1}, (f4v){e11, e01, c2, e12}, (f4v){e02, c3, e13, e03});
        store12(base + 3 * segF + off,
                (f4v){e00, e10, e20, e01}, (f4v){e11, e21, e02, e12}, (f4v){e22, e03, e13, e23});
    } else if (t == mainT) {
        for (int f = mainT * 4; f < F; ++f) {
            const int a = faces[3 * f + 0];
            const int bb = faces[3 * f + 1];
            const int c = faces[3 * f + 2];
            const int e0 = fte[3 * f + 0] + V_CONST;
            const int e1 = fte[3 * f + 1] + V_CONST;
            const int e2 = fte[3 * f + 2] + V_CONST;
            float* o0 = base + 3 * f;
            float* o1 = o0 + 3 * F;
            float* o2 = o1 + 3 * F;
            float* o3 = o2 + 3 * F;
            o0[0] = (float)a;  o0[1] = (float)e2; o0[2] = (float)e1;
            o1[0] = (float)bb; o1[1] = (float)e0; o1[2] = (float)e2;
            o2[0] = (float)c;  o2[1] = (float)e1; o2[2] = (float)e0;
            o3[0] = (float)e0; o3[1] = (float)e1; o3[2] = (float)e2;
        }
    }
}

extern "C" void kernel_launch(void* const* d_in, const int* in_sizes, int n_in,
                              void* d_out, int out_size, void* d_ws, size_t ws_size,
                              hipStream_t stream) {
    const float* verts = (const float*)d_in[0];
    const int* faces   = (const int*)d_in[1];
    const int* edges   = (const int*)d_in[2];
    const int* fte     = (const int*)d_in[3];
    float* out = (float*)d_out;

    const int F = in_sizes[1] / 3;
    const int E = in_sizes[2] / 2;
    const int N = in_sizes[0] / (V_CONST * 3);

    const int rowStride3 = (V_CONST + E) * 3;    // per-batch new_verts stride
    const int baseOut    = N * rowStride3;       // start of new_faces region

    const int Bcopy = N * CPB;                   // 8 * 768 = 6144
    const int Bmid  = (E + 255) / 256;           // 12273
    const int Bfac  = ((F >> 2) + 1 + 255) / 256;
    const int blocks = Bcopy + Bmid + Bfac;

    fused_k<<<blocks, 256, 0, stream>>>(verts, (const int2*)edges, faces, fte,
                                        out, E, F, N, rowStride3, baseOut,
                                        Bcopy, Bmid);
}